// Round 6
// baseline (177.010 us; speedup 1.0000x reference)
//
#include <hip/hip_runtime.h>
#include <hip/hip_bf16.h>
#include <math.h>

// Problem constants
#define B_    8
#define T_    2048
#define NTOK  (B_ * T_)   // 16384 tokens
#define D_    512
#define E_    8
#define CAP   NTOK        // per-expert bucket capacity (worst case)

// router v6: 1024 blocks x 256 thr; 16 tok/block, 4 tok/wave,
// lane = (kidx 0..15) x (ts 0..3); each lane: 1 token, 32 k-values.
// 4 blocks/CU co-resident -> 4 waves/SIMD (R5 had 1/SIMD: latency-bound).
#define RV_TOK    16
#define RV_THR    256
#define XS_STRIDE 132     // fp32 row stride for x tile
#define WS_FLOATS 2108    // 128*16 + skew

typedef __attribute__((ext_vector_type(4))) float f32x4;
typedef __attribute__((ext_vector_type(8))) short short8;  // 8 bf16 (MFMA a/b frag)

__device__ __forceinline__ void async_load16(const void* g, void* l) {
    __builtin_amdgcn_global_load_lds(
        (const __attribute__((address_space(1))) unsigned int*)g,
        (__attribute__((address_space(3))) unsigned int*)l,
        16, 0, 0);
}

// ---------------------------------------------------------------------------
// Kernel 1: Wk[e][d][h] fp32 -> Wkt[e][h][d] bf16 (B^T layout for GEMM).
// ---------------------------------------------------------------------------
__global__ __launch_bounds__(256) void transpose_wk(
    const float* __restrict__ Wk, __hip_bfloat16* __restrict__ Wkt)
{
    __shared__ float tile[32][33];
    const int e  = blockIdx.z;
    const int d0 = blockIdx.x * 32;
    const int h0 = blockIdx.y * 32;
    const int tx = threadIdx.x, ty = threadIdx.y;

    const float* src = Wk + ((size_t)e * D_ + d0) * D_ + h0;
    #pragma unroll
    for (int r = ty; r < 32; r += 8)
        tile[r][tx] = src[(size_t)r * D_ + tx];
    __syncthreads();
    __hip_bfloat16* dst = Wkt + ((size_t)e * D_ + h0) * D_ + d0;
    #pragma unroll
    for (int r = ty; r < 32; r += 8)
        dst[(size_t)r * D_ + tx] = __float2bfloat16(tile[tx][r]);
}

// ---------------------------------------------------------------------------
// Kernel 2: router v6. Same dataflow as v5 (x staged+converted once, W
// staged per 128-k chunk, fp32 fma, k-split lanes) but 16 tok/block so the
// grid is 1024 blocks -> 4 waves/SIMD (v5's 512 blocks left 1 wave/SIMD and
// every barrier/HBM latency exposed: 35us at 9% VALU).
// ---------------------------------------------------------------------------
__global__ __launch_bounds__(RV_THR) void router_kernel(
    const float* __restrict__ x,     // [NTOK][D]
    const float* __restrict__ eps,   // [NTOK][E]
    const float* __restrict__ Wr,    // [D][E]
    const float* __restrict__ br,    // [E]
    const float* __restrict__ Wn,    // [D][E]
    const float* __restrict__ bn,    // [E]
    __hip_bfloat16* __restrict__ xb, // out: [NTOK][D] bf16
    uint4* __restrict__ top2)        // out: [NTOK] {i1|i2<<8, g1bits, g2bits}
{
    __shared__ float xs[RV_TOK * XS_STRIDE];  // 8.4 KB
    __shared__ float wsh[WS_FLOATS];          // 8.4 KB; row k at k*16+(k>>3)*4

    const int tid  = threadIdx.x;
    const int tok0 = blockIdx.x * RV_TOK;
    const int lane = tid & 63, wv = tid >> 6;
    const int kidx = lane >> 2, ts = lane & 3;
    const int tl = wv * 4 + ts;                // this lane's token
    const int wk = tid >> 1, wh = tid & 1;     // W stager: row, half

    float acc[16];  // [0..7]=x.Wr per expert, [8..15]=x.Wn
    #pragma unroll
    for (int c = 0; c < 16; ++c) acc[c] = 0.f;

    for (int kc = 0; kc < D_; kc += 128) {
        // stage x chunk [16 tok][128 k] + fused bf16 convert/store
        #pragma unroll
        for (int it = 0; it < 2; ++it) {
            const int f   = it * RV_THR + tid;      // f32x4 index in [0,512)
            const int row = f >> 5, col = (f & 31) * 4;
            const f32x4 v = *(const f32x4*)(x + (size_t)(tok0 + row) * D_ + kc + col);
            *(f32x4*)(xs + row * XS_STRIDE + col) = v;
            union { __hip_bfloat16 h[4]; uint2 u; } cv;
            cv.h[0] = __float2bfloat16(v.x); cv.h[1] = __float2bfloat16(v.y);
            cv.h[2] = __float2bfloat16(v.z); cv.h[3] = __float2bfloat16(v.w);
            *(uint2*)(xb + (size_t)(tok0 + row) * D_ + kc + col) = cv.u;
        }
        // stage W chunk [128 k][16 c] skewed; cols 0-7 = Wr, 8-15 = Wn
        {
            const float* src = (wh ? Wn : Wr) + (size_t)(kc + wk) * E_;
            const f32x4 w0 = *(const f32x4*)(src);
            const f32x4 w1 = *(const f32x4*)(src + 4);
            float* dst = wsh + wk * 16 + (wk >> 3) * 4 + wh * 8;
            *(f32x4*)(dst)     = w0;
            *(f32x4*)(dst + 4) = w1;
        }
        __syncthreads();

        // compute: this lane's 8 k-values of the chunk (k = kidx*8 + kk)
        const float* xra = xs + tl * XS_STRIDE + kidx * 8;
        const f32x4 xa0 = *(const f32x4*)(xra);
        const f32x4 xa1 = *(const f32x4*)(xra + 4);
        const float* wbase = wsh + kidx * 132;  // (kidx*8)*16 + kidx*4
        #pragma unroll
        for (int kk = 0; kk < 8; ++kk) {
            const float xav = (kk < 4) ? xa0[kk] : xa1[kk - 4];
            const float* wrow = wbase + kk * 16;
            #pragma unroll
            for (int c4 = 0; c4 < 4; ++c4) {
                const f32x4 w = *(const f32x4*)(wrow + c4 * 4);
                #pragma unroll
                for (int c = 0; c < 4; ++c)
                    acc[c4 * 4 + c] = fmaf(xav, w[c], acc[c4 * 4 + c]);
            }
        }
        __syncthreads();
    }

    // reduce across the 16 kidx lanes (stride 4): xor 4,8,16,32
    #pragma unroll
    for (int off = 4; off < 64; off <<= 1) {
        #pragma unroll
        for (int c = 0; c < 16; ++c)
            acc[c] += __shfl_xor(acc[c], off);
    }

    if (lane < 4) {  // kidx==0 lanes hold full dots for token tl
        const int tok = tok0 + tl;
        float nv[8];
        #pragma unroll
        for (int e = 0; e < 8; ++e) {
            const float nl = acc[8 + e] + bn[e];
            // jax.nn.softplus = max(z,0) + log1p(exp(-|z|))
            const float sp = fmaxf(nl, 0.f) + log1pf(expf(-fabsf(nl)));
            nv[e] = acc[e] + br[e] + eps[(size_t)tok * E_ + e] * sp;
        }
        // top-2, lax.top_k tie semantics (lowest index wins ties)
        int i1 = 0; float v1 = nv[0];
        #pragma unroll
        for (int e = 1; e < 8; ++e)
            if (nv[e] > v1) { v1 = nv[e]; i1 = e; }
        int i2 = -1; float v2 = -3.4e38f;
        #pragma unroll
        for (int e = 0; e < 8; ++e)
            if (e != i1 && nv[e] > v2) { v2 = nv[e]; i2 = e; }
        const float t  = expf(v2 - v1);
        const float g1 = 1.f / (1.f + t);
        const float g2 = t / (1.f + t);
        top2[tok] = make_uint4((unsigned)i1 | ((unsigned)i2 << 8),
                               __float_as_uint(g1), __float_as_uint(g2), 0u);
    }
}

// ---------------------------------------------------------------------------
// Kernel 3: bucket build. LDS histogram -> 8 global atomics per block.
// Entry: {tok | slot<<31, gate_bits}; slot = contribution plane.
// ---------------------------------------------------------------------------
__global__ __launch_bounds__(256) void bucket_kernel(
    const uint4* __restrict__ top2,
    int* __restrict__ counts,     // [E] pre-zeroed
    uint2* __restrict__ entries)  // [E][CAP]
{
    __shared__ int hist[E_];
    __shared__ int base[E_];
    const int tid = threadIdx.x;
    const int tok = blockIdx.x * 256 + tid;
    if (tid < E_) hist[tid] = 0;
    __syncthreads();
    const uint4 t = top2[tok];
    const int i1 = t.x & 0xff, i2 = (t.x >> 8) & 0xff;
    const int l1 = atomicAdd(&hist[i1], 1);
    const int l2 = atomicAdd(&hist[i2], 1);
    __syncthreads();
    if (tid < E_) base[tid] = atomicAdd(counts + tid, hist[tid]);
    __syncthreads();
    entries[(size_t)i1 * CAP + base[i1] + l1] = make_uint2((unsigned)tok, t.y);
    entries[(size_t)i2 * CAP + base[i2] + l2] =
        make_uint2((unsigned)tok | 0x80000000u, t.z);
}

// ---------------------------------------------------------------------------
// Kernel 4: grouped expert GEMM v2. Tile 128x256 (BN=256: R5's 128x128 was
// 409 TF, MFMA:stage 16:4 per iter with only 16 K-iters; 128x256 gives 32:6
// and exactly 512 active blocks = 2/CU, no tail). BK=32, 4 waves each
// computing 64x128 as 4x8 mfma_f32_16x16x32_bf16, global_load_lds staging.
// Epilogue: plain stores of g*(acc+bk) into bf16 slot planes.
// ---------------------------------------------------------------------------
__global__ __launch_bounds__(256, 2) void moe_gemm(
    const __hip_bfloat16* __restrict__ xb,   // [NTOK][D] bf16
    const __hip_bfloat16* __restrict__ wkt,  // [E][D(out)][D(in)] bf16 (B^T)
    const float* __restrict__ bk,            // [E][D]
    const int* __restrict__ counts,          // [E]
    const uint2* __restrict__ entries,       // [E][CAP]
    __hip_bfloat16* __restrict__ outg,       // [2][NTOK][D] bf16 slot planes
    float* __restrict__ out,                 // [NTOK][D] fp32 (atomic fallback)
    int use_slots)
{
    constexpr int BM = 128, BN = 256, BK = 32;
    __shared__ __hip_bfloat16 As[BM * BK];   // 8 KB
    __shared__ __hip_bfloat16 Bs[BN * BK];   // 16 KB
    __shared__ uint2 ent[BM];

    const int e  = blockIdx.z;
    const int mt = blockIdx.y;
    const int nt = blockIdx.x;
    const int cnt = counts[e];
    if (mt * BM >= cnt) return;

    const int tid = threadIdx.x;
    const int wave = tid >> 6, lane = tid & 63;

    if (tid < BM) {
        const int idx = mt * BM + tid;
        ent[tid] = (idx < cnt) ? entries[(size_t)e * CAP + idx] : make_uint2(0u, 0u);
    }
    __syncthreads();

    const int quad = lane >> 4, lr = lane & 15;
    const int wm = wave >> 1, wn = wave & 1;   // wave tile: rows wm*64, cols wn*128
    const int sub = lane >> 2, part = lane & 3;

    f32x4 acc[4][8];
    #pragma unroll
    for (int i = 0; i < 4; ++i)
        #pragma unroll
        for (int j = 0; j < 8; ++j) acc[i][j] = (f32x4){0.f, 0.f, 0.f, 0.f};

    // A staging: wave covers rows [wave*32, wave*32+32)
    const size_t tok0 = ent[wave * 32 + sub].x & 0x7fffffffu;
    const size_t tok1 = ent[wave * 32 + 16 + sub].x & 0x7fffffffu;
    // B staging: wave covers rows [wave*64, wave*64+64)
    const size_t brow0 = (size_t)e * D_ + nt * BN + wave * 64 + sub;

    for (int k0 = 0; k0 < D_; k0 += BK) {
        async_load16(xb + tok0 * D_ + k0 + part * 8, As + (wave * 32) * BK);
        async_load16(xb + tok1 * D_ + k0 + part * 8, As + (wave * 32 + 16) * BK);
        #pragma unroll
        for (int q = 0; q < 4; ++q)
            async_load16(wkt + (brow0 + q * 16) * D_ + k0 + part * 8,
                         Bs + (wave * 64 + q * 16) * BK);
        __syncthreads();

        short8 a[4], b[8];
        #pragma unroll
        for (int i = 0; i < 4; ++i)
            a[i] = *(const short8*)(As + (wm * 64 + i * 16 + lr) * BK + quad * 8);
        #pragma unroll
        for (int j = 0; j < 8; ++j)
            b[j] = *(const short8*)(Bs + (wn * 128 + j * 16 + lr) * BK + quad * 8);
        #pragma unroll
        for (int i = 0; i < 4; ++i)
            #pragma unroll
            for (int j = 0; j < 8; ++j)
                acc[i][j] = __builtin_amdgcn_mfma_f32_16x16x32_bf16(a[i], b[j], acc[i][j], 0, 0, 0);
        __syncthreads();
    }

    const int colbase = nt * BN + wn * 128 + lr;
    float bkv[8];
    #pragma unroll
    for (int j = 0; j < 8; ++j) bkv[j] = bk[e * D_ + colbase + j * 16];

    #pragma unroll
    for (int i = 0; i < 4; ++i) {
        #pragma unroll
        for (int r = 0; r < 4; ++r) {
            const int row = wm * 64 + i * 16 + quad * 4 + r;  // C: row = quad*4+reg
            if (mt * BM + row < cnt) {
                const uint2 en = ent[row];
                const unsigned ts2 = en.x;
                const float g = __uint_as_float(en.y);
                if (use_slots) {
                    __hip_bfloat16* orow = outg + ((size_t)(ts2 >> 31) * NTOK
                                          + (ts2 & 0x7fffffffu)) * D_ + colbase;
                    #pragma unroll
                    for (int j = 0; j < 8; ++j)
                        orow[j * 16] = __float2bfloat16(g * (acc[i][j][r] + bkv[j]));
                } else {
                    float* orow = out + (size_t)(ts2 & 0x7fffffffu) * D_ + colbase;
                    #pragma unroll
                    for (int j = 0; j < 8; ++j)
                        atomicAdd(orow + j * 16, g * (acc[i][j][r] + bkv[j]));
                }
            }
        }
    }
}

// ---------------------------------------------------------------------------
// Kernel 5: combine the two bf16 slot planes -> fp32 d_out. 8 elems/thread.
// ---------------------------------------------------------------------------
__global__ __launch_bounds__(256) void combine_kernel(
    const __hip_bfloat16* __restrict__ outg, float* __restrict__ out)
{
    const size_t i = ((size_t)blockIdx.x * 256 + threadIdx.x) * 8;
    const uint4 u0 = *(const uint4*)(outg + i);
    const uint4 u1 = *(const uint4*)(outg + (size_t)NTOK * D_ + i);
    const unsigned* a = (const unsigned*)&u0;
    const unsigned* b = (const unsigned*)&u1;
    float o[8];
    #pragma unroll
    for (int k = 0; k < 4; ++k) {
        o[2*k]   = __uint_as_float(a[k] << 16) + __uint_as_float(b[k] << 16);
        o[2*k+1] = __uint_as_float(a[k] & 0xffff0000u)
                 + __uint_as_float(b[k] & 0xffff0000u);
    }
    *(f32x4*)(out + i)     = *(f32x4*)(o);
    *(f32x4*)(out + i + 4) = *(f32x4*)(o + 4);
}

// ---------------------------------------------------------------------------
// Launch
// ---------------------------------------------------------------------------
extern "C" void kernel_launch(void* const* d_in, const int* in_sizes, int n_in,
                              void* d_out, int out_size, void* d_ws, size_t ws_size,
                              hipStream_t stream) {
    const float* x   = (const float*)d_in[0];
    const float* eps = (const float*)d_in[1];
    const float* Wr  = (const float*)d_in[2];
    const float* br  = (const float*)d_in[3];
    const float* Wn  = (const float*)d_in[4];
    const float* bn  = (const float*)d_in[5];
    const float* Wk  = (const float*)d_in[6];
    const float* bk  = (const float*)d_in[7];
    float* out = (float*)d_out;

    // workspace layout (256B-aligned)
    char* ws = (char*)d_ws;
    size_t off = 0;
    int* counts = (int*)(ws + off);                     off += 256;
    uint2* entries = (uint2*)(ws + off);                off += (size_t)E_ * CAP * 8;      // 1 MiB
    __hip_bfloat16* xb = (__hip_bfloat16*)(ws + off);   off += (size_t)NTOK * D_ * 2;     // 16 MiB
    __hip_bfloat16* wkt = (__hip_bfloat16*)(ws + off);  off += (size_t)E_ * D_ * D_ * 2;  // 4 MiB
    uint4* top2 = (uint4*)(ws + off);                   off += (size_t)NTOK * 16;         // 256 KiB
    __hip_bfloat16* outg = (__hip_bfloat16*)(ws + off); off += (size_t)2 * NTOK * D_ * 2; // 32 MiB
    const int use_slots = (ws_size >= off) ? 1 : 0;

    hipMemsetAsync(counts, 0, E_ * sizeof(int), stream);
    if (!use_slots)
        hipMemsetAsync(out, 0, (size_t)out_size * sizeof(float), stream);

    transpose_wk<<<dim3(16, 16, E_), dim3(32, 8), 0, stream>>>(Wk, wkt);
    router_kernel<<<dim3(NTOK / RV_TOK), dim3(RV_THR), 0, stream>>>(
        x, eps, Wr, br, Wn, bn, xb, top2);
    bucket_kernel<<<dim3(NTOK / 256), dim3(256), 0, stream>>>(top2, counts, entries);
    moe_gemm<<<dim3(D_ / 256, CAP / 128, E_), dim3(256), 0, stream>>>(
        xb, wkt, bk, counts, entries, outg, out, use_slots);
    if (use_slots)
        combine_kernel<<<dim3((NTOK * D_) / (256 * 8)), dim3(256), 0, stream>>>(outg, out);
}

// Round 7
// 168.542 us; speedup vs baseline: 1.0502x; 1.0502x over previous
//
#include <hip/hip_runtime.h>
#include <hip/hip_bf16.h>
#include <math.h>

// Problem constants
#define B_    8
#define T_    2048
#define NTOK  (B_ * T_)   // 16384 tokens
#define D_    512
#define E_    8
#define NPAIR 28          // unordered expert pairs (top-2 always distinct)
#define CAP   NTOK        // per-pair bucket capacity (worst case)

// router v6: 1024 blocks x 256 thr; 16 tok/block, 4 tok/wave.
#define RV_TOK    16
#define RV_THR    256
#define XS_STRIDE 132
#define WS_FLOATS 2108

typedef __attribute__((ext_vector_type(4))) float f32x4;
typedef __attribute__((ext_vector_type(8))) short short8;  // 8 bf16 (MFMA a/b frag)

__device__ __forceinline__ void async_load16(const void* g, void* l) {
    __builtin_amdgcn_global_load_lds(
        (const __attribute__((address_space(1))) unsigned int*)g,
        (__attribute__((address_space(3))) unsigned int*)l,
        16, 0, 0);
}

// ---------------------------------------------------------------------------
// Kernel 1: Wk[e][d][h] fp32 -> Wkt[e][h][d] bf16 (B^T layout for GEMM).
// ---------------------------------------------------------------------------
__global__ __launch_bounds__(256) void transpose_wk(
    const float* __restrict__ Wk, __hip_bfloat16* __restrict__ Wkt)
{
    __shared__ float tile[32][33];
    const int e  = blockIdx.z;
    const int d0 = blockIdx.x * 32;
    const int h0 = blockIdx.y * 32;
    const int tx = threadIdx.x, ty = threadIdx.y;

    const float* src = Wk + ((size_t)e * D_ + d0) * D_ + h0;
    #pragma unroll
    for (int r = ty; r < 32; r += 8)
        tile[r][tx] = src[(size_t)r * D_ + tx];
    __syncthreads();
    __hip_bfloat16* dst = Wkt + ((size_t)e * D_ + h0) * D_ + d0;
    #pragma unroll
    for (int r = ty; r < 32; r += 8)
        dst[(size_t)r * D_ + tx] = __float2bfloat16(tile[tx][r]);
}

// ---------------------------------------------------------------------------
// Kernel 2: router v6 (unchanged from R6). x staged+bf16-converted once,
// W staged per 128-k chunk, fp32 fma, k-split lanes; 1024 blocks.
// ---------------------------------------------------------------------------
__global__ __launch_bounds__(RV_THR) void router_kernel(
    const float* __restrict__ x,     // [NTOK][D]
    const float* __restrict__ eps,   // [NTOK][E]
    const float* __restrict__ Wr,    // [D][E]
    const float* __restrict__ br,    // [E]
    const float* __restrict__ Wn,    // [D][E]
    const float* __restrict__ bn,    // [E]
    __hip_bfloat16* __restrict__ xb, // out: [NTOK][D] bf16
    uint4* __restrict__ top2)        // out: [NTOK] {i1|i2<<8, g1bits, g2bits}
{
    __shared__ float xs[RV_TOK * XS_STRIDE];  // 8.4 KB
    __shared__ float wsh[WS_FLOATS];          // 8.4 KB; row k at k*16+(k>>3)*4

    const int tid  = threadIdx.x;
    const int tok0 = blockIdx.x * RV_TOK;
    const int lane = tid & 63, wv = tid >> 6;
    const int kidx = lane >> 2, ts = lane & 3;
    const int tl = wv * 4 + ts;                // this lane's token
    const int wk = tid >> 1, wh = tid & 1;     // W stager: row, half

    float acc[16];  // [0..7]=x.Wr per expert, [8..15]=x.Wn
    #pragma unroll
    for (int c = 0; c < 16; ++c) acc[c] = 0.f;

    for (int kc = 0; kc < D_; kc += 128) {
        // stage x chunk [16 tok][128 k] + fused bf16 convert/store
        #pragma unroll
        for (int it = 0; it < 2; ++it) {
            const int f   = it * RV_THR + tid;      // f32x4 index in [0,512)
            const int row = f >> 5, col = (f & 31) * 4;
            const f32x4 v = *(const f32x4*)(x + (size_t)(tok0 + row) * D_ + kc + col);
            *(f32x4*)(xs + row * XS_STRIDE + col) = v;
            union { __hip_bfloat16 h[4]; uint2 u; } cv;
            cv.h[0] = __float2bfloat16(v.x); cv.h[1] = __float2bfloat16(v.y);
            cv.h[2] = __float2bfloat16(v.z); cv.h[3] = __float2bfloat16(v.w);
            *(uint2*)(xb + (size_t)(tok0 + row) * D_ + kc + col) = cv.u;
        }
        // stage W chunk [128 k][16 c] skewed; cols 0-7 = Wr, 8-15 = Wn
        {
            const float* src = (wh ? Wn : Wr) + (size_t)(kc + wk) * E_;
            const f32x4 w0 = *(const f32x4*)(src);
            const f32x4 w1 = *(const f32x4*)(src + 4);
            float* dst = wsh + wk * 16 + (wk >> 3) * 4 + wh * 8;
            *(f32x4*)(dst)     = w0;
            *(f32x4*)(dst + 4) = w1;
        }
        __syncthreads();

        // compute: this lane's 8 k-values of the chunk (k = kidx*8 + kk)
        const float* xra = xs + tl * XS_STRIDE + kidx * 8;
        const f32x4 xa0 = *(const f32x4*)(xra);
        const f32x4 xa1 = *(const f32x4*)(xra + 4);
        const float* wbase = wsh + kidx * 132;  // (kidx*8)*16 + kidx*4
        #pragma unroll
        for (int kk = 0; kk < 8; ++kk) {
            const float xav = (kk < 4) ? xa0[kk] : xa1[kk - 4];
            const float* wrow = wbase + kk * 16;
            #pragma unroll
            for (int c4 = 0; c4 < 4; ++c4) {
                const f32x4 w = *(const f32x4*)(wrow + c4 * 4);
                #pragma unroll
                for (int c = 0; c < 4; ++c)
                    acc[c4 * 4 + c] = fmaf(xav, w[c], acc[c4 * 4 + c]);
            }
        }
        __syncthreads();
    }

    // reduce across the 16 kidx lanes (stride 4): xor 4,8,16,32
    #pragma unroll
    for (int off = 4; off < 64; off <<= 1) {
        #pragma unroll
        for (int c = 0; c < 16; ++c)
            acc[c] += __shfl_xor(acc[c], off);
    }

    if (lane < 4) {  // kidx==0 lanes hold full dots for token tl
        const int tok = tok0 + tl;
        float nv[8];
        #pragma unroll
        for (int e = 0; e < 8; ++e) {
            const float nl = acc[8 + e] + bn[e];
            // jax.nn.softplus = max(z,0) + log1p(exp(-|z|))
            const float sp = fmaxf(nl, 0.f) + log1pf(expf(-fabsf(nl)));
            nv[e] = acc[e] + br[e] + eps[(size_t)tok * E_ + e] * sp;
        }
        // top-2, lax.top_k tie semantics (lowest index wins ties)
        int i1 = 0; float v1 = nv[0];
        #pragma unroll
        for (int e = 1; e < 8; ++e)
            if (nv[e] > v1) { v1 = nv[e]; i1 = e; }
        int i2 = -1; float v2 = -3.4e38f;
        #pragma unroll
        for (int e = 0; e < 8; ++e)
            if (e != i1 && nv[e] > v2) { v2 = nv[e]; i2 = e; }
        const float t  = expf(v2 - v1);
        const float g1 = 1.f / (1.f + t);
        const float g2 = t / (1.f + t);
        top2[tok] = make_uint4((unsigned)i1 | ((unsigned)i2 << 8),
                               __float_as_uint(g1), __float_as_uint(g2), 0u);
    }
}

// ---------------------------------------------------------------------------
// Kernel 3: PAIR bucket build. Token -> one of 28 expert-pair buckets
// (top-2 experts are always distinct). LDS histogram -> 28 global atomics
// per block. Entry: {tok, gate(e_lo), gate(e_hi), 0}.
// Pair id for a<b: p = a*(15-a)/2 + (b-a-1).
// ---------------------------------------------------------------------------
__global__ __launch_bounds__(256) void bucket_kernel(
    const uint4* __restrict__ top2,
    int* __restrict__ counts,     // [NPAIR] pre-zeroed
    uint4* __restrict__ entries)  // [NPAIR][CAP]
{
    __shared__ int hist[NPAIR];
    __shared__ int base[NPAIR];
    const int tid = threadIdx.x;
    const int tok = blockIdx.x * 256 + tid;
    if (tid < NPAIR) hist[tid] = 0;
    __syncthreads();
    const uint4 t = top2[tok];
    const int i1 = t.x & 0xff, i2 = (t.x >> 8) & 0xff;
    const int a = min(i1, i2), b = max(i1, i2);
    const unsigned ga = (i1 < i2) ? t.y : t.z;   // gate of expert a
    const unsigned gb = (i1 < i2) ? t.z : t.y;   // gate of expert b
    const int p = a * (15 - a) / 2 + (b - a - 1);
    const int l = atomicAdd(&hist[p], 1);
    __syncthreads();
    if (tid < NPAIR) base[tid] = atomicAdd(counts + tid, hist[tid]);
    __syncthreads();
    entries[(size_t)p * CAP + base[p] + l] = make_uint4((unsigned)tok, ga, gb, 0u);
}

// ---------------------------------------------------------------------------
// Kernel 4: pair-grouped expert GEMM, DIRECT output (no combine stage).
// Block = (pair p, 128-row tile, 128-col tile). A-tile staged once, run
// against BOTH Wk[e1] and Wk[e2] (32 MFMA/iter/wave = BN=256's ratio at
// BN=128's LDS footprint). Epilogue: out = ga*(C1+bk1)+gb*(C2+bk2), final
// fp32 plain stores -- kills outg planes (67MB) + combine kernel (~11us).
// ---------------------------------------------------------------------------
__global__ __launch_bounds__(256, 2) void moe_gemm(
    const __hip_bfloat16* __restrict__ xb,   // [NTOK][D] bf16
    const __hip_bfloat16* __restrict__ wkt,  // [E][D(out)][D(in)] bf16 (B^T)
    const float* __restrict__ bk,            // [E][D]
    const int* __restrict__ counts,          // [NPAIR]
    const uint4* __restrict__ entries,       // [NPAIR][CAP]
    float* __restrict__ out)                 // [NTOK][D] fp32 (fully written)
{
    constexpr int BM = 128, BN = 128, BK = 32;
    __shared__ __hip_bfloat16 As[BM * BK];       // 8 KB
    __shared__ __hip_bfloat16 Bs[2][BN * BK];    // 16 KB
    __shared__ uint4 ent[BM];                    // 2 KB

    const int p  = blockIdx.z;
    const int mt = blockIdx.y;
    const int nt = blockIdx.x;
    const int cnt = counts[p];
    if (mt * BM >= cnt) return;

    // decode pair p -> (e1 < e2)
    int e1 = 0, rem = p;
    while (rem >= 7 - e1) { rem -= 7 - e1; ++e1; }
    const int e2 = e1 + 1 + rem;

    const int tid = threadIdx.x;
    const int wave = tid >> 6, lane = tid & 63;

    if (tid < BM) {
        const int idx = mt * BM + tid;
        ent[tid] = (idx < cnt) ? entries[(size_t)p * CAP + idx]
                               : make_uint4(0u, 0u, 0u, 0u);
    }
    __syncthreads();

    const int quad = lane >> 4, lr = lane & 15;
    const int wm = wave >> 1, wn = wave & 1;
    const int sub = lane >> 2, part = lane & 3;

    f32x4 accA[4][4], accB[4][4];
    #pragma unroll
    for (int i = 0; i < 4; ++i)
        #pragma unroll
        for (int j = 0; j < 4; ++j) {
            accA[i][j] = (f32x4){0.f, 0.f, 0.f, 0.f};
            accB[i][j] = (f32x4){0.f, 0.f, 0.f, 0.f};
        }

    const size_t tok0 = ent[wave * 32 + sub].x;
    const size_t tok1 = ent[wave * 32 + 16 + sub].x;
    const size_t brow1 = (size_t)e1 * D_ + nt * BN + wave * 32 + sub;
    const size_t brow2 = (size_t)e2 * D_ + nt * BN + wave * 32 + sub;

    for (int k0 = 0; k0 < D_; k0 += BK) {
        async_load16(xb + tok0 * D_ + k0 + part * 8, As + (wave * 32) * BK);
        async_load16(xb + tok1 * D_ + k0 + part * 8, As + (wave * 32 + 16) * BK);
        async_load16(wkt + brow1 * D_ + k0 + part * 8, Bs[0] + (wave * 32) * BK);
        async_load16(wkt + (brow1 + 16) * D_ + k0 + part * 8, Bs[0] + (wave * 32 + 16) * BK);
        async_load16(wkt + brow2 * D_ + k0 + part * 8, Bs[1] + (wave * 32) * BK);
        async_load16(wkt + (brow2 + 16) * D_ + k0 + part * 8, Bs[1] + (wave * 32 + 16) * BK);
        __syncthreads();

        short8 a[4], b1[4], b2[4];
        #pragma unroll
        for (int i = 0; i < 4; ++i)
            a[i] = *(const short8*)(As + (wm * 64 + i * 16 + lr) * BK + quad * 8);
        #pragma unroll
        for (int j = 0; j < 4; ++j) {
            b1[j] = *(const short8*)(Bs[0] + (wn * 64 + j * 16 + lr) * BK + quad * 8);
            b2[j] = *(const short8*)(Bs[1] + (wn * 64 + j * 16 + lr) * BK + quad * 8);
        }
        #pragma unroll
        for (int i = 0; i < 4; ++i)
            #pragma unroll
            for (int j = 0; j < 4; ++j) {
                accA[i][j] = __builtin_amdgcn_mfma_f32_16x16x32_bf16(a[i], b1[j], accA[i][j], 0, 0, 0);
                accB[i][j] = __builtin_amdgcn_mfma_f32_16x16x32_bf16(a[i], b2[j], accB[i][j], 0, 0, 0);
            }
        __syncthreads();
    }

    const int colbase = nt * BN + wn * 64 + lr;
    float bkA[4], bkB[4];
    #pragma unroll
    for (int j = 0; j < 4; ++j) {
        bkA[j] = bk[e1 * D_ + colbase + j * 16];
        bkB[j] = bk[e2 * D_ + colbase + j * 16];
    }

    #pragma unroll
    for (int i = 0; i < 4; ++i) {
        #pragma unroll
        for (int r = 0; r < 4; ++r) {
            const int row = wm * 64 + i * 16 + quad * 4 + r;  // C: row = quad*4+reg
            if (mt * BM + row < cnt) {
                const uint4 en = ent[row];
                const float ga = __uint_as_float(en.y);
                const float gb = __uint_as_float(en.z);
                float* orow = out + (size_t)en.x * D_ + colbase;
                #pragma unroll
                for (int j = 0; j < 4; ++j)
                    orow[j * 16] = ga * (accA[i][j][r] + bkA[j])
                                 + gb * (accB[i][j][r] + bkB[j]);
            }
        }
    }
}

// ---------------------------------------------------------------------------
// Launch
// ---------------------------------------------------------------------------
extern "C" void kernel_launch(void* const* d_in, const int* in_sizes, int n_in,
                              void* d_out, int out_size, void* d_ws, size_t ws_size,
                              hipStream_t stream) {
    const float* x   = (const float*)d_in[0];
    const float* eps = (const float*)d_in[1];
    const float* Wr  = (const float*)d_in[2];
    const float* br  = (const float*)d_in[3];
    const float* Wn  = (const float*)d_in[4];
    const float* bn  = (const float*)d_in[5];
    const float* Wk  = (const float*)d_in[6];
    const float* bk  = (const float*)d_in[7];
    float* out = (float*)d_out;

    // workspace layout (256B-aligned): ~28 MB total
    char* ws = (char*)d_ws;
    size_t off = 0;
    int* counts = (int*)(ws + off);                     off += 256;
    uint4* entries = (uint4*)(ws + off);                off += (size_t)NPAIR * CAP * 16;  // 7.3 MiB
    __hip_bfloat16* xb = (__hip_bfloat16*)(ws + off);   off += (size_t)NTOK * D_ * 2;     // 16 MiB
    __hip_bfloat16* wkt = (__hip_bfloat16*)(ws + off);  off += (size_t)E_ * D_ * D_ * 2;  // 4 MiB
    uint4* top2 = (uint4*)(ws + off);                   off += (size_t)NTOK * 16;         // 256 KiB
    (void)ws_size;

    hipMemsetAsync(counts, 0, NPAIR * sizeof(int), stream);

    transpose_wk<<<dim3(16, 16, E_), dim3(32, 8), 0, stream>>>(Wk, wkt);
    router_kernel<<<dim3(NTOK / RV_TOK), dim3(RV_THR), 0, stream>>>(
        x, eps, Wr, br, Wn, bn, xb, top2);
    bucket_kernel<<<dim3(NTOK / 256), dim3(256), 0, stream>>>(top2, counts, entries);
    moe_gemm<<<dim3(D_ / 128, CAP / 128, NPAIR), dim3(256), 0, stream>>>(
        xb, wkt, bk, counts, entries, out);
}